// Round 8
// baseline (238.689 us; speedup 1.0000x reference)
//
#include <hip/hip_runtime.h>

// CenterLoss: loss = 0.5/B * (FF - 2*DOT + CC)
//   FF  = sum_i ||f_i||^2
//   DOT = sum_c S_c . newc_c           (S_c = sum of feats rows with label c)
//   CC  = sum_c count_c * ||newc_c||^2
//   newc_c = count_c>0 ? 0.5*centers_c + 0.5*S_c/count_c : centers_c
//
// R8 structure: NO sort/gather (random 1KB-granule gathers cap at ~1.4 TB/s on
// this chip regardless of concurrency — R4/R6/R7 evidence). Instead stream
// feats in natural row order; reduce into an LDS class table.
//   grid = 32 slabs x 8 dim-slices (256 blocks, 1/CU; LDS table 1000x36 floats)
//   block (j,s): rows j*4096.., dims s*32..s*32+31; wave-load = 8 consecutive
//   rows' 128B slice segments (float4/lane, monotone addresses).
//   ds_add_f32 accumulate -> dump 128KB partial (streaming stores)
//   k_epi: per-class reduce of 32 slab partials + DOT/CC; last block -> loss.

#define DDIM 256
#define NSLICE 8
#define SLABS 32
#define TSTRIDE 36            // floats per class in LDS table (16B-aligned, bank-spread)
#define NCLASS_MAX 1000

// ws (ints): counts[1024] | scalars[16] | part[8*C*32*32 floats]
// scalars: [0]=FF [1]=DOT [2]=CC, ticket at slot 12

__global__ __launch_bounds__(1024) void k0_zero(int* __restrict__ counts,
                                                int* __restrict__ scal16) {
    int t = threadIdx.x;
    counts[t] = 0;
    if (t < 16) scal16[t] = 0;
}

__global__ __launch_bounds__(256) void k1_hist(const int* __restrict__ labels,
                                               int* __restrict__ counts,
                                               int B, int C) {
    __shared__ int h[1024];
    for (int i = threadIdx.x; i < 1024; i += 256) h[i] = 0;
    __syncthreads();
    int stride = gridDim.x * 256;
    for (int i = blockIdx.x * 256 + threadIdx.x; i < B; i += stride)
        atomicAdd(&h[labels[i]], 1);
    __syncthreads();
    for (int i = threadIdx.x; i < C; i += 256) {
        int v = h[i];
        if (v) atomicAdd(&counts[i], v);
    }
}

// Streaming pass: block (slab j, slice s). 8 waves; wave w owns a contiguous
// 512-row subrange. Per group of 8 rows: lane = (row-in-group, float4-seg);
// one coalesced float4 load per lane (monotone through the slab), then 4
// LDS float atomics into the class table. FF accumulated in registers.
__global__ __launch_bounds__(512) void k_stream(const float4* __restrict__ feats4,
                                                const int* __restrict__ labels,
                                                float* __restrict__ part,
                                                float* __restrict__ scalars,
                                                int B, int C) {
    __shared__ float table[NCLASS_MAX * TSTRIDE];   // 144,000 B
    __shared__ float red[8];

    int s = blockIdx.x & 7;           // dim slice
    int j = blockIdx.x >> 3;          // slab
    int t = threadIdx.x, wave = t >> 6, lane = t & 63;

    int tsz = C * TSTRIDE;
    for (int i = t; i < tsz; i += 512) table[i] = 0.f;
    __syncthreads();

    int rows_per_slab = B / SLABS;                // 4096
    int rows_per_wave = rows_per_slab / 8;        // 512
    int r0 = j * rows_per_slab + wave * rows_per_wave;

    int rsub = lane >> 3;             // row within group of 8
    int seg  = lane & 7;              // float4 segment within 128B slice
    float ff = 0.f;

    // feats4 layout: row*64 float4s; slice s at float4 offset s*8.
    const float4* fbase = feats4 + (size_t)s * 8 + seg;

    int base = 0;
    for (; base + 32 <= rows_per_wave; base += 32) {
        int ra = r0 + base + rsub;
        int rb = ra + 8, rc = ra + 16, rd = ra + 24;
        // 4 independent coalesced loads (+ 4 broadcast label loads)
        float4 va = fbase[(size_t)ra * 64];
        float4 vb = fbase[(size_t)rb * 64];
        float4 vc = fbase[(size_t)rc * 64];
        float4 vd = fbase[(size_t)rd * 64];
        int ca = labels[ra], cb = labels[rb], cc = labels[rc], cd = labels[rd];

        ff += va.x*va.x + va.y*va.y + va.z*va.z + va.w*va.w;
        ff += vb.x*vb.x + vb.y*vb.y + vb.z*vb.z + vb.w*vb.w;
        ff += vc.x*vc.x + vc.y*vc.y + vc.z*vc.z + vc.w*vc.w;
        ff += vd.x*vd.x + vd.y*vd.y + vd.z*vd.z + vd.w*vd.w;

        int ba = ca * TSTRIDE + seg * 4;
        atomicAdd(&table[ba + 0], va.x); atomicAdd(&table[ba + 1], va.y);
        atomicAdd(&table[ba + 2], va.z); atomicAdd(&table[ba + 3], va.w);
        int bb = cb * TSTRIDE + seg * 4;
        atomicAdd(&table[bb + 0], vb.x); atomicAdd(&table[bb + 1], vb.y);
        atomicAdd(&table[bb + 2], vb.z); atomicAdd(&table[bb + 3], vb.w);
        int bc = cc * TSTRIDE + seg * 4;
        atomicAdd(&table[bc + 0], vc.x); atomicAdd(&table[bc + 1], vc.y);
        atomicAdd(&table[bc + 2], vc.z); atomicAdd(&table[bc + 3], vc.w);
        int bd = cd * TSTRIDE + seg * 4;
        atomicAdd(&table[bd + 0], vd.x); atomicAdd(&table[bd + 1], vd.y);
        atomicAdd(&table[bd + 2], vd.z); atomicAdd(&table[bd + 3], vd.w);
    }
    for (; base + 8 <= rows_per_wave; base += 8) {   // tail (unused at B=131072)
        int ra = r0 + base + rsub;
        float4 va = fbase[(size_t)ra * 64];
        int ca = labels[ra];
        ff += va.x*va.x + va.y*va.y + va.z*va.z + va.w*va.w;
        int ba = ca * TSTRIDE + seg * 4;
        atomicAdd(&table[ba + 0], va.x); atomicAdd(&table[ba + 1], va.y);
        atomicAdd(&table[ba + 2], va.z); atomicAdd(&table[ba + 3], va.w);
    }
    __syncthreads();

    // Dump partial: part[s][c][j][0..31], 16B-aligned vector copies.
    int nchunk = C * 8;   // 8 float4 per class
    for (int idx = t; idx < nchunk; idx += 512) {
        int c = idx >> 3, q = idx & 7;
        float4 v = *(const float4*)&table[c * TSTRIDE + q * 4];
        size_t off = (((size_t)(s * C + c)) * SLABS + j) * 32 + q * 4;
        *(float4*)&part[off] = v;
    }

    // FF reduction
#pragma unroll
    for (int off = 32; off > 0; off >>= 1) ff += __shfl_down(ff, off);
    if (lane == 0) red[wave] = ff;
    __syncthreads();
    if (t == 0) {
        float a = 0.f;
#pragma unroll
        for (int w = 0; w < 8; ++w) a += red[w];
        atomicAdd(&scalars[0], a);
    }
}

// One block per class: reduce 32 slab partials per slice (wave s handles
// slice s: 4KB contiguous), compute DOT/CC vs centers, last block -> loss.
__global__ __launch_bounds__(512) void k_epi(const float* __restrict__ part,
                                             const float* __restrict__ centers,
                                             const int* __restrict__ counts,
                                             float* __restrict__ scalars,
                                             int* __restrict__ ticket,
                                             float* __restrict__ out,
                                             int C, float invB) {
    __shared__ float red2[16];
    int c = blockIdx.x;
    int t = threadIdx.x, s = t >> 6, lane = t & 63;
    int d = lane & 31, jh = lane >> 5;

    const float* base = part + (((size_t)(s * C + c)) * SLABS) * 32;
    float acc = 0.f;
    for (int jj = jh; jj < SLABS; jj += 2) acc += base[jj * 32 + d];
    acc += __shfl_xor(acc, 32);     // full slab-sum per dim, in both halves

    int count = counts[c];
    float dotv = 0.f, ccv = 0.f;
    if (lane < 32) {
        float co = centers[c * DDIM + s * 32 + d];
        float nc = (count > 0) ? 0.5f * co + 0.5f * acc / (float)count : co;
        dotv = nc * acc;                    // count==0 -> acc==0 -> 0
        ccv  = nc * nc * (float)count;      // count==0 -> 0
    }
#pragma unroll
    for (int off = 16; off > 0; off >>= 1) {
        dotv += __shfl_down(dotv, off);
        ccv  += __shfl_down(ccv, off);
    }
    if (lane == 0) { red2[s * 2] = dotv; red2[s * 2 + 1] = ccv; }
    __syncthreads();
    if (t == 0) {
        float dsum = 0.f, csum = 0.f;
#pragma unroll
        for (int w = 0; w < 8; ++w) { dsum += red2[w * 2]; csum += red2[w * 2 + 1]; }
        atomicAdd(&scalars[1], dsum);
        atomicAdd(&scalars[2], csum);
        __threadfence();
        int old = atomicAdd(ticket, 1);
        if (old == C - 1) {
            __threadfence();
            float A  = atomicAdd(&scalars[0], 0.f);
            float Bv = atomicAdd(&scalars[1], 0.f);
            float E  = atomicAdd(&scalars[2], 0.f);
            out[0] = 0.5f * invB * (A - 2.f * Bv + E);
        }
    }
}

extern "C" void kernel_launch(void* const* d_in, const int* in_sizes, int n_in,
                              void* d_out, int out_size, void* d_ws, size_t ws_size,
                              hipStream_t stream) {
    const float* feats   = (const float*)d_in[0];
    const float* centers = (const float*)d_in[1];
    const int*   labels  = (const int*)d_in[2];

    int B = in_sizes[2];              // 131072
    int Dv = in_sizes[0] / B;         // 256 (kernel assumes 256)
    int C = in_sizes[1] / Dv;         // 1000
    (void)Dv; (void)n_in; (void)ws_size; (void)out_size;

    int* W = (int*)d_ws;
    int* counts    = W;                        // 1024 ints
    float* scalars = (float*)(W + 1024);       // 16: [0]FF [1]DOT [2]CC
    int* ticket    = W + 1024 + 12;            // scalars slot 12
    float* part    = (float*)(W + 1040);       // 8*C*32*32 floats (~32.8 MB)

    k0_zero<<<1, 1024, 0, stream>>>(counts, W + 1024);
    k1_hist<<<256, 256, 0, stream>>>(labels, counts, B, C);
    k_stream<<<SLABS * NSLICE, 512, 0, stream>>>((const float4*)feats, labels,
                                                 part, scalars, B, C);
    k_epi<<<C, 512, 0, stream>>>(part, centers, counts, scalars, ticket,
                                 (float*)d_out, C, 1.0f / (float)B);
}

// Round 9
// 130.983 us; speedup vs baseline: 1.8223x; 1.8223x over previous
//
#include <hip/hip_runtime.h>

// CenterLoss: loss = 0.5/B * (FF - 2*DOT + CC)
//   FF  = sum_i ||f_i||^2
//   DOT = sum_c S_c . newc_c           (S_c = sum of feats rows with label c)
//   CC  = sum_c count_c * ||newc_c||^2
//   newc_c = count_c>0 ? 0.5*centers_c + 0.5*S_c/count_c : centers_c
//
// R9: span-gather. Counting-sort rowidx; each WAVE owns 64 contiguous sorted
// positions. All 64 indices+labels prefetched in 2 lane-parallel loads; inner
// loop is 8 independent row loads per step with broadcast (shfl) addressing —
// no barriers, no LDS, no index loads on the hot path. Class boundaries
// (labels non-decreasing along span, ~1.5/span) flush the register
// accumulator via 4 global float atomics/lane into sums[C][D]. Epilogue
// kernel computes DOT/CC from sums/counts/centers; last block emits loss.

#define DDIM 256
#define NHB 64            // histogram partial blocks
#define HPAD 1024

// ws (ints): counts[1024] | offsets[1024] | cursor[1024] | scalars[16]
//            | hist_part[NHB*1024] | sums[C*256 floats] | rowidx[B]
// scalars: [0]=FF [1]=DOT [2]=CC, ticket at slot 12

__global__ __launch_bounds__(256) void k1_hist(const int* __restrict__ labels,
                                               int* __restrict__ hist_part,
                                               float* __restrict__ sums,
                                               float* __restrict__ scal16,
                                               int B, int C) {
    __shared__ int h[1024];
    int b = blockIdx.x, t = threadIdx.x;
    for (int i = t; i < 1024; i += 256) h[i] = 0;
    __syncthreads();
    int per = (B + NHB - 1) / NHB;
    int base = b * per;
    int end = min(B, base + per);
    for (int i = base + t; i < end; i += 256) atomicAdd(&h[labels[i]], 1);
    __syncthreads();
    for (int i = t; i < 1024; i += 256) hist_part[b * HPAD + i] = h[i];
    // zero sums (C*64 float4) cooperatively across the NHB blocks
    int nf4 = C * (DDIM / 4);
    float4* s4 = (float4*)sums;
    float4 z = make_float4(0.f, 0.f, 0.f, 0.f);
    for (int i = b * 256 + t; i < nf4; i += NHB * 256) s4[i] = z;
    if (b == 0 && t < 16) scal16[t] = 0.f;
}

// Reduce NHB partials per class, Hillis-Steele scan -> counts/offsets/cursor.
__global__ __launch_bounds__(1024) void k2_scan(const int* __restrict__ hist_part,
                                                int* __restrict__ counts,
                                                int* __restrict__ offsets,
                                                int* __restrict__ cursor, int C) {
    __shared__ int sc[1024];
    int t = threadIdx.x;
    int v = 0;
    for (int b = 0; b < NHB; ++b) v += hist_part[b * HPAD + t];
    sc[t] = v;
    __syncthreads();
    for (int off = 1; off < 1024; off <<= 1) {
        int add = (t >= off) ? sc[t - off] : 0;
        __syncthreads();
        sc[t] += add;
        __syncthreads();
    }
    if (t < C) {
        int e = sc[t] - v;
        counts[t] = v;
        offsets[t] = e;
        cursor[t]  = e;
    }
}

__global__ __launch_bounds__(256) void k3_scatter(const int* __restrict__ labels,
                                                  int* __restrict__ cursor,
                                                  int* __restrict__ rowidx, int B) {
    int stride = gridDim.x * 256;
    for (int i = blockIdx.x * 256 + threadIdx.x; i < B; i += stride) {
        int c = labels[i];
        int pos = atomicAdd(&cursor[c], 1);
        rowidx[pos] = i;
    }
}

// Span gather: wave g owns sorted positions [g*64, g*64+64). No LDS/barriers.
__global__ __launch_bounds__(256) void k4_span(const float4* __restrict__ feats4,
                                               const int* __restrict__ rowidx,
                                               const int* __restrict__ labels,
                                               float* __restrict__ sums,
                                               float* __restrict__ scalars, int B) {
    int t = threadIdx.x, wave = t >> 6, lane = t & 63;
    int g = blockIdx.x * 4 + wave;
    int start = g * 64;
    if (start >= B) return;
    int n = min(64, B - start);

    // lane-parallel prefetch of the whole span's indices and labels
    int p = start + ((lane < n) ? lane : (n - 1));
    int ridx = rowidx[p];
    int lbl  = labels[ridx];

    float4 acc = make_float4(0.f, 0.f, 0.f, 0.f);
    float ff = 0.f;
    int cur = __shfl(lbl, 0);

#define FLUSH() do { float* bp = &sums[cur * DDIM + lane * 4];              \
        atomicAdd(bp + 0, acc.x); atomicAdd(bp + 1, acc.y);                 \
        atomicAdd(bp + 2, acc.z); atomicAdd(bp + 3, acc.w); } while (0)

#define ROWK(IDX, V) { int ck = __shfl(lbl, (IDX));                         \
        if (ck != cur) { FLUSH(); acc = make_float4(0.f,0.f,0.f,0.f); cur = ck; } \
        acc.x += V.x; acc.y += V.y; acc.z += V.z; acc.w += V.w; }

    if (n == 64) {
        for (int i = 0; i < 64; i += 8) {
            int r0 = __shfl(ridx, i + 0), r1 = __shfl(ridx, i + 1);
            int r2 = __shfl(ridx, i + 2), r3 = __shfl(ridx, i + 3);
            int r4 = __shfl(ridx, i + 4), r5 = __shfl(ridx, i + 5);
            int r6 = __shfl(ridx, i + 6), r7 = __shfl(ridx, i + 7);
            // 8 independent 16B loads in flight
            float4 v0 = feats4[r0 * 64 + lane];
            float4 v1 = feats4[r1 * 64 + lane];
            float4 v2 = feats4[r2 * 64 + lane];
            float4 v3 = feats4[r3 * 64 + lane];
            float4 v4 = feats4[r4 * 64 + lane];
            float4 v5 = feats4[r5 * 64 + lane];
            float4 v6 = feats4[r6 * 64 + lane];
            float4 v7 = feats4[r7 * 64 + lane];

            ff += v0.x*v0.x + v0.y*v0.y + v0.z*v0.z + v0.w*v0.w;
            ff += v1.x*v1.x + v1.y*v1.y + v1.z*v1.z + v1.w*v1.w;
            ff += v2.x*v2.x + v2.y*v2.y + v2.z*v2.z + v2.w*v2.w;
            ff += v3.x*v3.x + v3.y*v3.y + v3.z*v3.z + v3.w*v3.w;
            ff += v4.x*v4.x + v4.y*v4.y + v4.z*v4.z + v4.w*v4.w;
            ff += v5.x*v5.x + v5.y*v5.y + v5.z*v5.z + v5.w*v5.w;
            ff += v6.x*v6.x + v6.y*v6.y + v6.z*v6.z + v6.w*v6.w;
            ff += v7.x*v7.x + v7.y*v7.y + v7.z*v7.z + v7.w*v7.w;

            int c0 = __shfl(lbl, i + 0), c7 = __shfl(lbl, i + 7);
            if (c0 == cur && c7 == cur) {
                // labels non-decreasing: c0==c7==cur => whole group is cur
                acc.x += v0.x + v1.x + v2.x + v3.x + v4.x + v5.x + v6.x + v7.x;
                acc.y += v0.y + v1.y + v2.y + v3.y + v4.y + v5.y + v6.y + v7.y;
                acc.z += v0.z + v1.z + v2.z + v3.z + v4.z + v5.z + v6.z + v7.z;
                acc.w += v0.w + v1.w + v2.w + v3.w + v4.w + v5.w + v6.w + v7.w;
            } else {
                ROWK(i + 0, v0); ROWK(i + 1, v1); ROWK(i + 2, v2); ROWK(i + 3, v3);
                ROWK(i + 4, v4); ROWK(i + 5, v5); ROWK(i + 6, v6); ROWK(i + 7, v7);
            }
        }
    } else {
        for (int i = 0; i < n; ++i) {
            int r = __shfl(ridx, i);
            float4 v = feats4[r * 64 + lane];
            ff += v.x*v.x + v.y*v.y + v.z*v.z + v.w*v.w;
            ROWK(i, v);
        }
    }
    FLUSH();

#pragma unroll
    for (int off = 32; off > 0; off >>= 1) ff += __shfl_xor(ff, off);
    if (lane == 0) atomicAdd(&scalars[0], ff);
#undef ROWK
#undef FLUSH
}

// One 64-thread block per class: DOT/CC from sums/counts/centers; last -> loss.
__global__ __launch_bounds__(64) void k_epi(const float* __restrict__ sums,
                                            const float* __restrict__ centers,
                                            const int* __restrict__ counts,
                                            float* __restrict__ scalars,
                                            int* __restrict__ ticket,
                                            float* __restrict__ out,
                                            int C, float invB) {
    int c = blockIdx.x, lane = threadIdx.x;
    float4 s  = *(const float4*)&sums[c * DDIM + lane * 4];
    float4 co = *(const float4*)&centers[c * DDIM + lane * 4];
    int n = counts[c];
    float inv = (n > 0) ? 0.5f / (float)n : 0.f;
    float4 nc;
    nc.x = 0.5f * co.x + s.x * inv;   // n==0: s==0,n==0 -> dotv=ccv=0 regardless
    nc.y = 0.5f * co.y + s.y * inv;
    nc.z = 0.5f * co.z + s.z * inv;
    nc.w = 0.5f * co.w + s.w * inv;
    float dotv = nc.x * s.x + nc.y * s.y + nc.z * s.z + nc.w * s.w;
    float ccv  = (nc.x*nc.x + nc.y*nc.y + nc.z*nc.z + nc.w*nc.w) * (float)n;

#pragma unroll
    for (int off = 32; off > 0; off >>= 1) {
        dotv += __shfl_down(dotv, off);
        ccv  += __shfl_down(ccv, off);
    }
    if (lane == 0) {
        atomicAdd(&scalars[1], dotv);
        atomicAdd(&scalars[2], ccv);
        __threadfence();
        int old = atomicAdd(ticket, 1);
        if (old == C - 1) {
            __threadfence();
            float A  = atomicAdd(&scalars[0], 0.f);
            float Bv = atomicAdd(&scalars[1], 0.f);
            float E  = atomicAdd(&scalars[2], 0.f);
            out[0] = 0.5f * invB * (A - 2.f * Bv + E);
        }
    }
}

extern "C" void kernel_launch(void* const* d_in, const int* in_sizes, int n_in,
                              void* d_out, int out_size, void* d_ws, size_t ws_size,
                              hipStream_t stream) {
    const float* feats   = (const float*)d_in[0];
    const float* centers = (const float*)d_in[1];
    const int*   labels  = (const int*)d_in[2];

    int B = in_sizes[2];              // 131072
    int Dv = in_sizes[0] / B;         // 256 (kernel assumes 256)
    int C = in_sizes[1] / Dv;         // 1000 (<=1024 assumed)
    (void)Dv; (void)n_in; (void)ws_size; (void)out_size;

    int* W = (int*)d_ws;
    int* counts    = W;                          // 1024
    int* offsets   = W + 1024;                   // 1024
    int* cursor    = W + 2048;                   // 1024
    float* scalars = (float*)(W + 3072);         // 16: [0]FF [1]DOT [2]CC
    int* ticket    = W + 3072 + 12;              // scalars slot 12
    int* hist_part = W + 3072 + 16;              // NHB*1024
    float* sums    = (float*)(hist_part + NHB * HPAD);  // C*256 (16B aligned)
    int* rowidx    = (int*)(sums + C * DDIM);    // B

    k1_hist<<<NHB, 256, 0, stream>>>(labels, hist_part, sums, scalars, B, C);
    k2_scan<<<1, 1024, 0, stream>>>(hist_part, counts, offsets, cursor, C);
    int sblocks = (B + 255) / 256;
    if (sblocks > 512) sblocks = 512;
    k3_scatter<<<sblocks, 256, 0, stream>>>(labels, cursor, rowidx, B);
    int gblocks = (B + 255) / 256;               // 4 waves x 64 rows per block
    k4_span<<<gblocks, 256, 0, stream>>>((const float4*)feats, rowidx, labels,
                                         sums, scalars, B);
    k_epi<<<C, 64, 0, stream>>>(sums, centers, counts, scalars, ticket,
                                (float*)d_out, C, 1.0f / (float)B);
}